// Round 5
// baseline (819.732 us; speedup 1.0000x reference)
//
#include <hip/hip_runtime.h>
#include <hip/hip_bf16.h>
#include <hip/hip_fp16.h>
#include <math.h>

#define HD    128
#define EIN   325
#define PST   136      // pqr/x1/ef tile row stride (f16), 16B-aligned rows (272 B)
#define NST   264      // node A-tile row stride (f16)
#define XST   136      // node x1 tile row stride
#define IST   408      // init A-tile row stride (400+8)

typedef _Float16 half8 __attribute__((ext_vector_type(8)));
typedef _Float16 half2v __attribute__((ext_vector_type(2)));
typedef float    floatx16 __attribute__((ext_vector_type(16)));

__device__ __forceinline__ float silu_f(float x) {
    return x / (1.0f + __expf(-x));
}

// ---- generic weight prep: fp32 [m][Ktot][Nn] rows [krow0, krow0+Kact) -> fp16 [m][Nn][Kpad]
__global__ void k_wprep(const float* __restrict__ src, _Float16* __restrict__ dst,
                        int Ktot, int krow0, int Kact, int Nn, int Kpad, int nmat) {
    int idx = blockIdx.x * 256 + threadIdx.x;
    int per = Nn * Kpad;
    if (idx >= nmat * per) return;
    int m = idx / per, r = idx - m * per;
    int n = r / Kpad, k = r - n * Kpad;
    float v = (k < Kact) ? src[(size_t)m * Ktot * Nn + (size_t)(krow0 + k) * Nn + n] : 0.f;
    dst[idx] = (_Float16)v;
}

// ---- tiny kernels ----
__global__ void k_latip(const float* __restrict__ lat, float* __restrict__ latip, int G) {
    int idx = blockIdx.x * 256 + threadIdx.x;
    if (idx >= G * 9) return;
    int g = idx / 9, ij = idx - g * 9, i = ij / 3, k = ij - (ij / 3) * 3;
    const float* L = lat + g * 9;
    latip[idx] = L[i*3+0]*L[k*3+0] + L[i*3+1]*L[k*3+1] + L[i*3+2]*L[k*3+2];
}

__global__ void k_hist(const int* __restrict__ ei1, int* __restrict__ cnt, int E) {
    int idx = blockIdx.x * 256 + threadIdx.x;
    if (idx < E) atomicAdd(&cnt[ei1[idx]], 1);
}

__global__ void k_deginv(const int* __restrict__ cnt, float* __restrict__ deginv, int N) {
    int idx = blockIdx.x * 256 + threadIdx.x;
    if (idx < N) deginv[idx] = 1.0f / fmaxf((float)cnt[idx], 1.0f);
}

__global__ __launch_bounds__(1024) void k_scan(const int* __restrict__ cnt,
                                               int* __restrict__ head, int N) {
    __shared__ int part[1024];
    int tid = threadIdx.x;
    int chunk = (N + 1023) >> 10;
    int start = tid * chunk, stop = min(start + chunk, N);
    int s = 0;
    for (int i = start; i < stop; ++i) s += cnt[i];
    part[tid] = s;
    __syncthreads();
    for (int off = 1; off < 1024; off <<= 1) {
        int v = (tid >= off) ? part[tid - off] : 0;
        __syncthreads();
        part[tid] += v;
        __syncthreads();
    }
    int run = (tid > 0) ? part[tid - 1] : 0;
    for (int i = start; i < stop; ++i) { head[i] = run; run += cnt[i]; }
}

__global__ void k_scatter(const int* __restrict__ ei1, int* __restrict__ head,
                          int* __restrict__ perm, int E) {
    int e = blockIdx.x * 256 + threadIdx.x;
    if (e < E) {
        int d = ei1[e];
        int pos = atomicAdd(&head[d], 1);
        perm[pos] = e;
    }
}

// ---- sorted edge meta ----
__global__ void k_esort(const int* __restrict__ ei, const int* __restrict__ n2g,
                        const float* __restrict__ fc, const int* __restrict__ perm,
                        int* __restrict__ eaS, int* __restrict__ ebS, int* __restrict__ egS,
                        float* __restrict__ fdS, int E) {
    int s = blockIdx.x * 256 + threadIdx.x;
    if (s >= E) return;
    int e = perm[s];
    int a = ei[e], b = ei[E + e];
    eaS[s] = a; ebS[s] = b; egS[s] = n2g[a];
    #pragma unroll
    for (int d = 0; d < 3; ++d) {
        float sh = fc[b * 3 + d] - fc[a * 3 + d];
        fdS[s * 3 + d] = sh - floorf(sh + 0.5f + 1e-4f);
    }
}

// ---- per-graph table: R[l][g][c] = latip[g] @ W1lat[l] + eb1[l] ----
__global__ void k_rlat(const float* __restrict__ latip, const float* __restrict__ ew1,
                       const float* __restrict__ eb1, _Float16* __restrict__ R16, int G) {
    int idx = blockIdx.x * 256 + threadIdx.x;
    if (idx >= 4 * G * HD) return;
    int l = idx / (G * HD), r = idx - l * (G * HD), g = r >> 7, c = r & 127;
    const float* W  = ew1 + (size_t)l * EIN * HD + 256 * HD;  // k-rows 256..264
    const float* lp = latip + g * 9;
    float s = eb1[l * HD + c];
    #pragma unroll
    for (int j = 0; j < 9; ++j) s = fmaf(lp[j], W[j * HD + c], s);
    R16[idx] = (_Float16)s;
}

__global__ void k_fin(const float* __restrict__ outsum, const float* __restrict__ deginv,
                      float* __restrict__ out, int N) {
    int idx = blockIdx.x * 256 + threadIdx.x;
    if (idx < N * 3) out[idx] = outsum[idx] * deginv[idx / 3];
}

// ---- node init fused with first P/Q ----
__global__ __launch_bounds__(256) void k_init_pq(
    const int* __restrict__ at, const float* __restrict__ t,
    const float* __restrict__ embed, const _Float16* __restrict__ latwT,
    const float* __restrict__ lat_b, float* __restrict__ h,
    _Float16* __restrict__ h16,
    const _Float16* __restrict__ WaT, const _Float16* __restrict__ WbT,
    _Float16* __restrict__ P16, _Float16* __restrict__ Q16, int N)
{
    __shared__ __align__(16) _Float16 xs[64 * IST];   // 51 KB
    __shared__ int   atL[64];
    __shared__ float tL[64];
    int tid = threadIdx.x;
    int n0  = blockIdx.x * 64;

    if (tid < 64) {
        int node = n0 + tid;
        atL[tid] = (node < N) ? at[node] - 1 : 0;
        tL[tid]  = (node < N) ? t[node] : 0.f;
    }
    __syncthreads();

    for (int c = tid; c < 64 * 32; c += 256) {       // embed cols 0..127
        int row = c >> 5, p = c & 31;
        float4 v = {0, 0, 0, 0};
        if (n0 + row < N) v = *(const float4*)(embed + (size_t)atL[row] * HD + p * 4);
        _Float16* d = xs + row * IST + p * 4;
        d[0] = (_Float16)v.x; d[1] = (_Float16)v.y; d[2] = (_Float16)v.z; d[3] = (_Float16)v.w;
    }
    for (int c = tid; c < 64 * 272; c += 256) {      // sin/cos cols 128..383 + pad
        int row = c / 272, j = c - row * 272;
        float v = 0.f;
        if (j < 256 && n0 + row < N) {
            int k = j & 127;
            float fr = __expf(-(float)k * 0.07252236514f);
            float a = tL[row] * fr;
            v = (j < 128) ? __sinf(a) : __cosf(a);
        }
        xs[row * IST + 128 + j] = (_Float16)v;
    }
    __syncthreads();

    int lane = tid & 63, wv = tid >> 6;
    int l31 = lane & 31, lh = lane >> 5;
    int rm = (wv >> 1) * 32, cb = (wv & 1) * 64;
    int n0c = cb + l31, n1c = cb + 32 + l31;

    floatx16 acc0 = {}, acc1 = {};
    {
        const _Float16* ap  = xs + (size_t)(rm + l31) * IST + lh * 8;
        const _Float16* bp0 = latwT + (size_t)n0c * 400 + lh * 8;
        const _Float16* bp1 = latwT + (size_t)n1c * 400 + lh * 8;
        for (int ks = 0; ks < 25; ++ks) {
            half8 a  = *(const half8*)(ap  + ks * 16);
            acc0 = __builtin_amdgcn_mfma_f32_32x32x16_f16(a, *(const half8*)(bp0 + ks * 16), acc0, 0, 0, 0);
            acc1 = __builtin_amdgcn_mfma_f32_32x32x16_f16(a, *(const half8*)(bp1 + ks * 16), acc1, 0, 0, 0);
        }
    }
    __syncthreads();

    {
        float b0 = lat_b[n0c], b1v = lat_b[n1c];
        #pragma unroll
        for (int r = 0; r < 16; ++r) {
            int row = rm + (r & 3) + 8 * (r >> 2) + 4 * lh;
            int node = n0 + row;
            float v0 = acc0[r] + b0, v1 = acc1[r] + b1v;
            _Float16 h0 = (_Float16)v0, h1 = (_Float16)v1;
            if (node < N) {
                h[(size_t)node * HD + n0c] = v0;
                h[(size_t)node * HD + n1c] = v1;
                h16[(size_t)node * HD + n0c] = h0;
                h16[(size_t)node * HD + n1c] = h1;
            }
            xs[row * PST + n0c] = h0;
            xs[row * PST + n1c] = h1;
        }
    }
    __syncthreads();

    {
        const _Float16* BT  = (wv & 1) ? WbT : WaT;
        _Float16*       OUT = (wv & 1) ? Q16 : P16;
        floatx16 acc[4] = {};
        const _Float16* ap = xs + (size_t)(rm + l31) * PST + lh * 8;
        for (int ks = 0; ks < 8; ++ks) {
            half8 a = *(const half8*)(ap + ks * 16);
            #pragma unroll
            for (int i = 0; i < 4; ++i) {
                half8 b = *(const half8*)(BT + (size_t)(i * 32 + l31) * HD + ks * 16 + lh * 8);
                acc[i] = __builtin_amdgcn_mfma_f32_32x32x16_f16(a, b, acc[i], 0, 0, 0);
            }
        }
        #pragma unroll
        for (int r = 0; r < 16; ++r) {
            int row = rm + (r & 3) + 8 * (r >> 2) + 4 * lh;
            int node = n0 + row;
            if (node < N) {
                #pragma unroll
                for (int i = 0; i < 4; ++i)
                    OUT[(size_t)node * HD + i * 32 + l31] = (_Float16)acc[i][r];
            }
        }
    }
}

// ---- barrier-free edge kernel: each wave owns 32 edges x all 128 cols ----
// block = 128 edges, 4 waves, NO __syncthreads anywhere.
#define PUTF(kk, val) { const int _ks = (kk) >> 4, _j = (kk) & 15;                       \
    afrag[_ks][_j & 7] = (lh == (_j >> 3)) ? (_Float16)(val) : afrag[_ks][_j & 7]; }

template <bool LAST>
__global__ __launch_bounds__(256, 4) void k_edge(
    const int* __restrict__ eaS, const int* __restrict__ ebS,
    const int* __restrict__ egS, const float* __restrict__ fdS,
    const _Float16* __restrict__ P16, const _Float16* __restrict__ Q16,
    const _Float16* __restrict__ R16, const _Float16* __restrict__ WdT,
    const _Float16* __restrict__ W2T, const float* __restrict__ b2,
    const _Float16* __restrict__ cw1T, const float* __restrict__ cb1,
    const float* __restrict__ cw2,
    float* __restrict__ aggsum, float* __restrict__ outsum, int E)
{
    __shared__ __align__(16) _Float16 xt[128 * PST];   // 34.8 KB: pqr -> x1 -> ef
    __shared__ int   eaL[128], ebL[128], egL[128];
    __shared__ float fdlL[128][3];
    __shared__ float gateL[128];

    int tid  = threadIdx.x;
    int lane = tid & 63, wv = tid >> 6;
    int l31  = lane & 31, lh = lane >> 5;
    int r0   = wv * 32;                 // block-local slab base for this wave
    int s0   = blockIdx.x * 128;

    // per-wave meta load (lanes 0..31 of each wave)
    if (lane < 32) {
        int s = s0 + r0 + l31;
        int row = r0 + l31;
        if (s < E) {
            eaL[row] = eaS[s]; ebL[row] = ebS[s]; egL[row] = egS[s];
            fdlL[row][0] = fdS[s * 3];
            fdlL[row][1] = fdS[s * 3 + 1];
            fdlL[row][2] = fdS[s * 3 + 2];
        } else {
            eaL[row] = 0; ebL[row] = -1; egL[row] = 0;
            fdlL[row][0] = fdlL[row][1] = fdlL[row][2] = 0.f;
        }
    }

    // stage PQR for this wave's 32 rows: 32 rows x 16 half8 chunks
    for (int i = lane; i < 32 * 16; i += 64) {
        int row = r0 + (i >> 4), p = i & 15;
        int b = ebL[row] < 0 ? 0 : ebL[row];
        half8 pv = *(const half8*)(P16 + (size_t)eaL[row] * HD + p * 8);
        half8 qv = *(const half8*)(Q16 + (size_t)b * HD + p * 8);
        half8 rv = *(const half8*)(R16 + (size_t)egL[row] * HD + p * 8);
        half8 s = pv + qv + rv;
        *(half8*)(xt + row * PST + p * 8) = s;
    }

    // dis A-fragment in registers (row = r0+l31, k = 16ks+8lh+j) via Chebyshev
    half8 afrag[4];
    #pragma unroll
    for (int i = 0; i < 4; ++i)
        #pragma unroll
        for (int j = 0; j < 8; ++j) afrag[i][j] = (_Float16)0.f;
    {
        int er = r0 + l31;
        float fdv[3] = {fdlL[er][0], fdlL[er][1], fdlL[er][2]};
        #pragma unroll
        for (int d = 0; d < 3; ++d) {
            float ang = 6.283185307179586f * fdv[d];
            float s1 = __sinf(ang), c1 = __cosf(ang);
            float two_c1 = 2.f * c1;
            PUTF(30 + 10 * d + 0, 1.0f);      // cos w=0
            PUTF(10 * d + 1, s1);
            PUTF(30 + 10 * d + 1, c1);
            float sm2 = 0.f, sm1 = s1, cm2 = 1.f, cm1 = c1;
            #pragma unroll
            for (int wq = 2; wq < 10; ++wq) {
                float sn = two_c1 * sm1 - sm2;
                float cn = two_c1 * cm1 - cm2;
                PUTF(10 * d + wq, sn);
                PUTF(30 + 10 * d + wq, cn);
                sm2 = sm1; sm1 = sn; cm2 = cm1; cm1 = cn;
            }
        }
    }

    // ---- GEMM1: dis @ Wd, K=64, 4 col-tiles ----
    floatx16 acc[4] = {};
    #pragma unroll
    for (int ks = 0; ks < 4; ++ks) {
        #pragma unroll
        for (int c = 0; c < 4; ++c) {
            half8 b = *(const half8*)(WdT + (size_t)(c * 32 + l31) * 64 + ks * 16 + lh * 8);
            acc[c] = __builtin_amdgcn_mfma_f32_32x32x16_f16(afrag[ks], b, acc[c], 0, 0, 0);
        }
    }

    // x1 = silu(acc + PQR), in place (lane-exclusive positions, within-wave ordering)
    #pragma unroll
    for (int c = 0; c < 4; ++c) {
        #pragma unroll
        for (int r = 0; r < 16; ++r) {
            int row = r0 + (r & 3) + 8 * (r >> 2) + 4 * lh;
            int col = c * 32 + l31;
            float v = acc[c][r] + (float)xt[row * PST + col];
            xt[row * PST + col] = (_Float16)silu_f(v);
        }
    }

    // ---- GEMM2: ef = silu(x1 @ W2 + b2), K=128 ----
    #pragma unroll
    for (int c = 0; c < 4; ++c) acc[c] = (floatx16){};
    {
        const _Float16* ap = xt + (size_t)(r0 + l31) * PST + lh * 8;
        for (int ks = 0; ks < 8; ++ks) {
            half8 a = *(const half8*)(ap + ks * 16);
            #pragma unroll
            for (int c = 0; c < 4; ++c) {
                half8 b = *(const half8*)(W2T + (size_t)(c * 32 + l31) * HD + ks * 16 + lh * 8);
                acc[c] = __builtin_amdgcn_mfma_f32_32x32x16_f16(a, b, acc[c], 0, 0, 0);
            }
        }
    }
    // ef -> xt in place
    #pragma unroll
    for (int c = 0; c < 4; ++c) {
        float bb = b2[c * 32 + l31];
        #pragma unroll
        for (int r = 0; r < 16; ++r) {
            int row = r0 + (r & 3) + 8 * (r >> 2) + 4 * lh;
            xt[row * PST + c * 32 + l31] = (_Float16)silu_f(acc[c][r] + bb);
        }
    }

    if (!LAST) {
        // run-reduced scatter: wave scans its 32 rows; lane owns cols 2*lane, 2*lane+1
        int c2 = lane * 2;
        float sx = 0.f, sy = 0.f;
        int cur = -1;
        for (int r = 0; r < 32; ++r) {
            int row = r0 + r;
            int d = ebL[row];
            half2v v = *(const half2v*)(xt + row * PST + c2);
            float vx = (float)v[0], vy = (float)v[1];
            if (d != cur) {
                if (cur >= 0) {
                    atomicAdd(&aggsum[(size_t)cur * HD + c2],     sx);
                    atomicAdd(&aggsum[(size_t)cur * HD + c2 + 1], sy);
                }
                cur = d; sx = vx; sy = vy;
            } else { sx += vx; sy += vy; }
        }
        if (cur >= 0) {
            atomicAdd(&aggsum[(size_t)cur * HD + c2],     sx);
            atomicAdd(&aggsum[(size_t)cur * HD + c2 + 1], sy);
        }
    } else {
        // GEMM3: g1 = silu(ef @ cw1 + cb1); gate = g1 @ cw2
        floatx16 acc3[4] = {};
        {
            const _Float16* ap = xt + (size_t)(r0 + l31) * PST + lh * 8;
            for (int ks = 0; ks < 8; ++ks) {
                half8 a = *(const half8*)(ap + ks * 16);
                #pragma unroll
                for (int c = 0; c < 4; ++c) {
                    half8 b = *(const half8*)(cw1T + (size_t)(c * 32 + l31) * HD + ks * 16 + lh * 8);
                    acc3[c] = __builtin_amdgcn_mfma_f32_32x32x16_f16(a, b, acc3[c], 0, 0, 0);
                }
            }
        }
        float cbv[4], wv2[4];
        #pragma unroll
        for (int c = 0; c < 4; ++c) { cbv[c] = cb1[c * 32 + l31]; wv2[c] = cw2[c * 32 + l31]; }
        #pragma unroll
        for (int r = 0; r < 16; ++r) {
            float p = 0.f;
            #pragma unroll
            for (int c = 0; c < 4; ++c) p += silu_f(acc3[c][r] + cbv[c]) * wv2[c];
            p += __shfl_xor(p, 16);
            p += __shfl_xor(p, 8);
            p += __shfl_xor(p, 4);
            p += __shfl_xor(p, 2);
            p += __shfl_xor(p, 1);
            if (l31 == 0) {
                int row = r0 + (r & 3) + 8 * (r >> 2) + 4 * lh;
                gateL[row] = p;   // unique row per (reg, lh) -> plain write
            }
        }
        // output scatter: lanes 0..2 handle dims x/y/z over the wave's 32 rows
        if (lane < 3) {
            int dim = lane;
            float s = 0.f;
            int cur = -1;
            for (int r = 0; r < 32; ++r) {
                int row = r0 + r;
                int d = ebL[row];
                float v = fdlL[row][dim] * gateL[row];
                if (d != cur) {
                    if (cur >= 0) atomicAdd(&outsum[cur * 3 + dim], s);
                    cur = d; s = v;
                } else s += v;
            }
            if (cur >= 0) atomicAdd(&outsum[cur * 3 + dim], s);
        }
    }
}

// ---- fused node update + next-layer P/Q ----
__global__ __launch_bounds__(256) void k_node_pq(
    float* __restrict__ h, _Float16* __restrict__ h16,
    float* __restrict__ aggsum, const float* __restrict__ deginv,
    const _Float16* __restrict__ W1T, const float* __restrict__ b1,
    const _Float16* __restrict__ W2T, const float* __restrict__ b2,
    const _Float16* __restrict__ WaT, const _Float16* __restrict__ WbT,
    _Float16* __restrict__ P16, _Float16* __restrict__ Q16, int N)
{
    __shared__ __align__(16) _Float16 xs[64 * NST];   // 33.8 KB
    _Float16* x1s = xs;

    int tid = threadIdx.x;
    int n0  = blockIdx.x * 64;

    for (int c = tid; c < 64 * 16; c += 256) {
        int row = c >> 4, p = c & 15;
        int node = n0 + row;
        uint4 v = {0, 0, 0, 0};
        if (node < N) v = *(const uint4*)(h16 + (size_t)node * HD + p * 8);
        *(uint4*)(xs + row * NST + p * 8) = v;
    }
    for (int c = tid; c < 64 * HD; c += 256) {
        int row = c >> 7, cc = c & 127;
        int node = n0 + row;
        float v = 0.f;
        if (node < N) {
            size_t gi = (size_t)node * HD + cc;
            v = aggsum[gi] * deginv[node];
            aggsum[gi] = 0.f;
        }
        xs[row * NST + HD + cc] = (_Float16)v;
    }
    __syncthreads();

    int lane = tid & 63, wv = tid >> 6;
    int l31 = lane & 31, lh = lane >> 5;
    int rm = (wv >> 1) * 32, cbase = (wv & 1) * 64;
    int n0c = cbase + l31, n1c = cbase + 32 + l31;

    floatx16 acc0 = {}, acc1 = {};
    {
        const _Float16* ap  = xs  + (size_t)(rm + l31) * NST + lh * 8;
        const _Float16* bp0 = W1T + (size_t)n0c * 256 + lh * 8;
        const _Float16* bp1 = W1T + (size_t)n1c * 256 + lh * 8;
        for (int ks = 0; ks < 16; ++ks) {
            half8 a  = *(const half8*)(ap  + ks * 16);
            acc0 = __builtin_amdgcn_mfma_f32_32x32x16_f16(a, *(const half8*)(bp0 + ks * 16), acc0, 0, 0, 0);
            acc1 = __builtin_amdgcn_mfma_f32_32x32x16_f16(a, *(const half8*)(bp1 + ks * 16), acc1, 0, 0, 0);
        }
    }
    __syncthreads();
    {
        float b10 = b1[n0c], b11 = b1[n1c];
        #pragma unroll
        for (int r = 0; r < 16; ++r) {
            int row = rm + (r & 3) + 8 * (r >> 2) + 4 * lh;
            x1s[row * XST + n0c] = (_Float16)silu_f(acc0[r] + b10);
            x1s[row * XST + n1c] = (_Float16)silu_f(acc1[r] + b11);
        }
    }
    __syncthreads();

    acc0 = {}; acc1 = {};
    {
        const _Float16* ap  = x1s + (size_t)(rm + l31) * XST + lh * 8;
        const _Float16* bp0 = W2T + (size_t)n0c * HD + lh * 8;
        const _Float16* bp1 = W2T + (size_t)n1c * HD + lh * 8;
        for (int ks = 0; ks < 8; ++ks) {
            half8 a  = *(const half8*)(ap  + ks * 16);
            acc0 = __builtin_amdgcn_mfma_f32_32x32x16_f16(a, *(const half8*)(bp0 + ks * 16), acc0, 0, 0, 0);
            acc1 = __builtin_amdgcn_mfma_f32_32x32x16_f16(a, *(const half8*)(bp1 + ks * 16), acc1, 0, 0, 0);
        }
    }
    __syncthreads();

    {
        float b20 = b2[n0c], b21 = b2[n1c];
        #pragma unroll
        for (int r = 0; r < 16; ++r) {
            int row = rm + (r & 3) + 8 * (r >> 2) + 4 * lh;
            int node = n0 + row;
            float v0 = silu_f(acc0[r] + b20);
            float v1 = silu_f(acc1[r] + b21);
            _Float16 h0 = (_Float16)0.f, h1 = (_Float16)0.f;
            if (node < N) {
                size_t g0 = (size_t)node * HD + n0c;
                size_t g1 = (size_t)node * HD + n1c;
                v0 += h[g0]; v1 += h[g1];
                h[g0] = v0; h[g1] = v1;
                h0 = (_Float16)v0; h1 = (_Float16)v1;
                h16[g0] = h0; h16[g1] = h1;
            }
            xs[row * PST + n0c] = h0;
            xs[row * PST + n1c] = h1;
        }
    }
    __syncthreads();

    {
        const _Float16* BT  = (wv & 1) ? WbT : WaT;
        _Float16*       OUT = (wv & 1) ? Q16 : P16;
        floatx16 acc[4] = {};
        const _Float16* ap = xs + (size_t)(rm + l31) * PST + lh * 8;
        for (int ks = 0; ks < 8; ++ks) {
            half8 a = *(const half8*)(ap + ks * 16);
            #pragma unroll
            for (int i = 0; i < 4; ++i) {
                half8 b = *(const half8*)(BT + (size_t)(i * 32 + l31) * HD + ks * 16 + lh * 8);
                acc[i] = __builtin_amdgcn_mfma_f32_32x32x16_f16(a, b, acc[i], 0, 0, 0);
            }
        }
        #pragma unroll
        for (int r = 0; r < 16; ++r) {
            int row = rm + (r & 3) + 8 * (r >> 2) + 4 * lh;
            int node = n0 + row;
            if (node < N) {
                #pragma unroll
                for (int i = 0; i < 4; ++i)
                    OUT[(size_t)node * HD + i * 32 + l31] = (_Float16)acc[i][r];
            }
        }
    }
}

// ---------------- launcher ----------------
extern "C" void kernel_launch(void* const* d_in, const int* in_sizes, int n_in,
                              void* d_out, int out_size, void* d_ws, size_t ws_size,
                              hipStream_t stream)
{
    const int*   at    = (const int*)  d_in[0];
    const float* t     = (const float*)d_in[1];
    const float* fc    = (const float*)d_in[2];
    const int*   ei    = (const int*)  d_in[3];
    const float* lat   = (const float*)d_in[4];
    const int*   n2g   = (const int*)  d_in[5];
    const float* embed = (const float*)d_in[6];
    const float* lat_w = (const float*)d_in[7];
    const float* lat_b = (const float*)d_in[8];
    const float* ew1   = (const float*)d_in[9];
    const float* eb1   = (const float*)d_in[10];
    const float* ew2   = (const float*)d_in[11];
    const float* eb2   = (const float*)d_in[12];
    const float* nw1   = (const float*)d_in[13];
    const float* nb1   = (const float*)d_in[14];
    const float* nw2   = (const float*)d_in[15];
    const float* nb2   = (const float*)d_in[16];
    const float* cw1   = (const float*)d_in[17];
    const float* cb1   = (const float*)d_in[18];
    const float* cw2   = (const float*)d_in[19];

    int N = in_sizes[0];
    int E = in_sizes[3] / 2;
    int G = in_sizes[4] / 9;

    // ---- workspace carve ----
    char* p = (char*)d_ws;
    float* h      = (float*)p;  p += (size_t)N * HD * 4;
    float* aggsum = (float*)p;  p += (size_t)N * HD * 4;   // zeroed below
    float* outsum = (float*)p;  p += (size_t)N * 3 * 4;    // zeroed below
    int*   cnt    = (int*)p;    p += (size_t)N * 4;        // zeroed below
    int*   head   = (int*)p;    p += (size_t)N * 4;
    float* deginv = (float*)p;  p += (size_t)N * 4;
    float* latip  = (float*)p;  p += (size_t)G * 9 * 4;
    int*   perm   = (int*)p;    p += (size_t)E * 4;
    int*   eaS    = (int*)p;    p += (size_t)E * 4;
    int*   ebS    = (int*)p;    p += (size_t)E * 4;
    int*   egS    = (int*)p;    p += (size_t)E * 4;
    float* fdS    = (float*)p;  p += (size_t)E * 3 * 4;
    _Float16* h16   = (_Float16*)p; p += (size_t)N * HD * 2;
    _Float16* P16   = (_Float16*)p; p += (size_t)N * HD * 2;
    _Float16* Q16   = (_Float16*)p; p += (size_t)N * HD * 2;
    _Float16* w1aT  = (_Float16*)p; p += (size_t)4 * HD * HD * 2;
    _Float16* w1bT  = (_Float16*)p; p += (size_t)4 * HD * HD * 2;
    _Float16* wdT   = (_Float16*)p; p += (size_t)4 * HD * 64 * 2;
    _Float16* w2T   = (_Float16*)p; p += (size_t)4 * HD * HD * 2;
    _Float16* nw1T  = (_Float16*)p; p += (size_t)3 * HD * 256 * 2;
    _Float16* nw2T  = (_Float16*)p; p += (size_t)3 * HD * HD * 2;
    _Float16* cw1T  = (_Float16*)p; p += (size_t)HD * HD * 2;
    _Float16* latwT = (_Float16*)p; p += (size_t)HD * 400 * 2;
    _Float16* R16   = (_Float16*)p; p += (size_t)4 * G * HD * 2;

    // zero aggsum|outsum|cnt (contiguous)
    hipMemsetAsync(aggsum, 0, ((size_t)N * HD + (size_t)N * 3 + N) * 4, stream);

    // weight prep (fp16, transposed, K-padded)
    {
        int tot;
        tot = 4 * HD * HD;  k_wprep<<<(tot+255)/256, 256, 0, stream>>>(ew1, w1aT, EIN, 0,   128, HD, HD, 4);
        tot = 4 * HD * HD;  k_wprep<<<(tot+255)/256, 256, 0, stream>>>(ew1, w1bT, EIN, 128, 128, HD, HD, 4);
        tot = 4 * HD * 64;  k_wprep<<<(tot+255)/256, 256, 0, stream>>>(ew1, wdT,  EIN, 265, 60,  HD, 64, 4);
        tot = 4 * HD * HD;  k_wprep<<<(tot+255)/256, 256, 0, stream>>>(ew2, w2T,  HD,  0,  128, HD, HD, 4);
        tot = 3 * HD * 256; k_wprep<<<(tot+255)/256, 256, 0, stream>>>(nw1, nw1T, 256, 0,  256, HD, 256, 3);
        tot = 3 * HD * HD;  k_wprep<<<(tot+255)/256, 256, 0, stream>>>(nw2, nw2T, HD,  0,  128, HD, HD, 3);
        tot = 1 * HD * HD;  k_wprep<<<(tot+255)/256, 256, 0, stream>>>(cw1, cw1T, HD,  0,  128, HD, HD, 1);
        tot = HD * 400;     k_wprep<<<(tot+255)/256, 256, 0, stream>>>(lat_w, latwT, 384, 0, 384, HD, 400, 1);
    }

    k_latip  <<<(G * 9 + 255) / 256, 256, 0, stream>>>(lat, latip, G);
    k_hist   <<<(E + 255) / 256,     256, 0, stream>>>(ei + E, cnt, E);
    k_scan   <<<1, 1024, 0, stream>>>(cnt, head, N);
    k_deginv <<<(N + 255) / 256,     256, 0, stream>>>(cnt, deginv, N);
    k_scatter<<<(E + 255) / 256,     256, 0, stream>>>(ei + E, head, perm, E);
    k_esort  <<<(E + 255) / 256,     256, 0, stream>>>(ei, n2g, fc, perm, eaS, ebS, egS, fdS, E);
    k_rlat   <<<(4 * G * HD + 255) / 256, 256, 0, stream>>>(latip, ew1, eb1, R16, G);
    k_init_pq<<<(N + 63) / 64, 256, 0, stream>>>(at, t, embed, latwT, lat_b, h, h16,
                                                 w1aT, w1bT, P16, Q16, N);

    int eblocks = (E + 127) / 128;
    int nblocks = (N + 63) / 64;
    for (int l = 0; l < 3; ++l) {
        k_edge<false><<<eblocks, 256, 0, stream>>>(eaS, ebS, egS, fdS, P16, Q16,
            R16 + (size_t)l * G * HD, wdT + (size_t)l * HD * 64,
            w2T + (size_t)l * HD * HD, eb2 + l * HD,
            cw1T, cb1, cw2, aggsum, outsum, E);
        k_node_pq<<<nblocks, 256, 0, stream>>>(h, h16, aggsum, deginv,
            nw1T + (size_t)l * HD * 256, nb1 + l * HD,
            nw2T + (size_t)l * HD * HD,  nb2 + l * HD,
            w1aT + (size_t)(l + 1) * HD * HD, w1bT + (size_t)(l + 1) * HD * HD,
            P16, Q16, N);
    }
    k_edge<true><<<eblocks, 256, 0, stream>>>(eaS, ebS, egS, fdS, P16, Q16,
        R16 + (size_t)3 * G * HD, wdT + (size_t)3 * HD * 64,
        w2T + (size_t)3 * HD * HD, eb2 + 3 * HD,
        cw1T, cb1, cw2, aggsum, outsum, E);

    k_fin<<<(N * 3 + 255) / 256, 256, 0, stream>>>(outsum, deginv, (float*)d_out, N);
}

// Round 6
// 727.947 us; speedup vs baseline: 1.1261x; 1.1261x over previous
//
#include <hip/hip_runtime.h>
#include <hip/hip_bf16.h>
#include <hip/hip_fp16.h>
#include <math.h>

#define HD    128
#define EIN   325
#define PST   136      // pqr/x1/ef tile row stride (f16), 16B-aligned rows (272 B)
#define NST   264      // node A-tile row stride (f16)
#define XST   136      // node x1 tile row stride
#define IST   408      // init A-tile row stride (400+8)

typedef _Float16 half8 __attribute__((ext_vector_type(8)));
typedef _Float16 half4v __attribute__((ext_vector_type(4)));
typedef _Float16 half2v __attribute__((ext_vector_type(2)));
typedef float    floatx16 __attribute__((ext_vector_type(16)));

__device__ __forceinline__ float silu_f(float x) {
    return x / (1.0f + __expf(-x));
}

// ---- generic weight prep: fp32 [m][Ktot][Nn] rows [krow0, krow0+Kact) -> fp16 [m][Nn][Kpad]
__global__ void k_wprep(const float* __restrict__ src, _Float16* __restrict__ dst,
                        int Ktot, int krow0, int Kact, int Nn, int Kpad, int nmat) {
    int idx = blockIdx.x * 256 + threadIdx.x;
    int per = Nn * Kpad;
    if (idx >= nmat * per) return;
    int m = idx / per, r = idx - m * per;
    int n = r / Kpad, k = r - n * Kpad;
    float v = (k < Kact) ? src[(size_t)m * Ktot * Nn + (size_t)(krow0 + k) * Nn + n] : 0.f;
    dst[idx] = (_Float16)v;
}

// ---- tiny kernels ----
__global__ void k_latip(const float* __restrict__ lat, float* __restrict__ latip, int G) {
    int idx = blockIdx.x * 256 + threadIdx.x;
    if (idx >= G * 9) return;
    int g = idx / 9, ij = idx - g * 9, i = ij / 3, k = ij - (ij / 3) * 3;
    const float* L = lat + g * 9;
    latip[idx] = L[i*3+0]*L[k*3+0] + L[i*3+1]*L[k*3+1] + L[i*3+2]*L[k*3+2];
}

__global__ void k_hist(const int* __restrict__ ei1, int* __restrict__ cnt, int E) {
    int idx = blockIdx.x * 256 + threadIdx.x;
    if (idx < E) atomicAdd(&cnt[ei1[idx]], 1);
}

__global__ void k_deginv(const int* __restrict__ cnt, float* __restrict__ deginv, int N) {
    int idx = blockIdx.x * 256 + threadIdx.x;
    if (idx < N) deginv[idx] = 1.0f / fmaxf((float)cnt[idx], 1.0f);
}

__global__ __launch_bounds__(1024) void k_scan(const int* __restrict__ cnt,
                                               int* __restrict__ head, int N) {
    __shared__ int part[1024];
    int tid = threadIdx.x;
    int chunk = (N + 1023) >> 10;
    int start = tid * chunk, stop = min(start + chunk, N);
    int s = 0;
    for (int i = start; i < stop; ++i) s += cnt[i];
    part[tid] = s;
    __syncthreads();
    for (int off = 1; off < 1024; off <<= 1) {
        int v = (tid >= off) ? part[tid - off] : 0;
        __syncthreads();
        part[tid] += v;
        __syncthreads();
    }
    int run = (tid > 0) ? part[tid - 1] : 0;
    for (int i = start; i < stop; ++i) { head[i] = run; run += cnt[i]; }
}

__global__ void k_scatter(const int* __restrict__ ei1, int* __restrict__ head,
                          int* __restrict__ perm, int E) {
    int e = blockIdx.x * 256 + threadIdx.x;
    if (e < E) {
        int d = ei1[e];
        int pos = atomicAdd(&head[d], 1);
        perm[pos] = e;
    }
}

// ---- sorted edge meta ----
__global__ void k_esort(const int* __restrict__ ei, const int* __restrict__ n2g,
                        const float* __restrict__ fc, const int* __restrict__ perm,
                        int* __restrict__ eaS, int* __restrict__ ebS, int* __restrict__ egS,
                        float* __restrict__ fdS, int E) {
    int s = blockIdx.x * 256 + threadIdx.x;
    if (s >= E) return;
    int e = perm[s];
    int a = ei[e], b = ei[E + e];
    eaS[s] = a; ebS[s] = b; egS[s] = n2g[a];
    #pragma unroll
    for (int d = 0; d < 3; ++d) {
        float sh = fc[b * 3 + d] - fc[a * 3 + d];
        fdS[s * 3 + d] = sh - floorf(sh + 0.5f + 1e-4f);
    }
}

// ---- per-graph table: R[l][g][c] = latip[g] @ W1lat[l] + eb1[l] ----
__global__ void k_rlat(const float* __restrict__ latip, const float* __restrict__ ew1,
                       const float* __restrict__ eb1, _Float16* __restrict__ R16, int G) {
    int idx = blockIdx.x * 256 + threadIdx.x;
    if (idx >= 4 * G * HD) return;
    int l = idx / (G * HD), r = idx - l * (G * HD), g = r >> 7, c = r & 127;
    const float* W  = ew1 + (size_t)l * EIN * HD + 256 * HD;  // k-rows 256..264
    const float* lp = latip + g * 9;
    float s = eb1[l * HD + c];
    #pragma unroll
    for (int j = 0; j < 9; ++j) s = fmaf(lp[j], W[j * HD + c], s);
    R16[idx] = (_Float16)s;
}

__global__ void k_fin(const float* __restrict__ outsum, const float* __restrict__ deginv,
                      float* __restrict__ out, int N) {
    int idx = blockIdx.x * 256 + threadIdx.x;
    if (idx < N * 3) out[idx] = outsum[idx] * deginv[idx / 3];
}

// ---- node init fused with first P/Q ----
__global__ __launch_bounds__(256) void k_init_pq(
    const int* __restrict__ at, const float* __restrict__ t,
    const float* __restrict__ embed, const _Float16* __restrict__ latwT,
    const float* __restrict__ lat_b, float* __restrict__ h,
    _Float16* __restrict__ h16,
    const _Float16* __restrict__ WaT, const _Float16* __restrict__ WbT,
    _Float16* __restrict__ P16, _Float16* __restrict__ Q16, int N)
{
    __shared__ __align__(16) _Float16 xs[64 * IST];   // 51 KB
    __shared__ int   atL[64];
    __shared__ float tL[64];
    int tid = threadIdx.x;
    int n0  = blockIdx.x * 64;

    if (tid < 64) {
        int node = n0 + tid;
        atL[tid] = (node < N) ? at[node] - 1 : 0;
        tL[tid]  = (node < N) ? t[node] : 0.f;
    }
    __syncthreads();

    for (int c = tid; c < 64 * 32; c += 256) {       // embed cols 0..127
        int row = c >> 5, p = c & 31;
        float4 v = {0, 0, 0, 0};
        if (n0 + row < N) v = *(const float4*)(embed + (size_t)atL[row] * HD + p * 4);
        _Float16* d = xs + row * IST + p * 4;
        d[0] = (_Float16)v.x; d[1] = (_Float16)v.y; d[2] = (_Float16)v.z; d[3] = (_Float16)v.w;
    }
    for (int c = tid; c < 64 * 272; c += 256) {      // sin/cos cols 128..383 + pad
        int row = c / 272, j = c - row * 272;
        float v = 0.f;
        if (j < 256 && n0 + row < N) {
            int k = j & 127;
            float fr = __expf(-(float)k * 0.07252236514f);
            float a = tL[row] * fr;
            v = (j < 128) ? __sinf(a) : __cosf(a);
        }
        xs[row * IST + 128 + j] = (_Float16)v;
    }
    __syncthreads();

    int lane = tid & 63, wv = tid >> 6;
    int l31 = lane & 31, lh = lane >> 5;
    int rm = (wv >> 1) * 32, cb = (wv & 1) * 64;
    int n0c = cb + l31, n1c = cb + 32 + l31;

    floatx16 acc0 = {}, acc1 = {};
    {
        const _Float16* ap  = xs + (size_t)(rm + l31) * IST + lh * 8;
        const _Float16* bp0 = latwT + (size_t)n0c * 400 + lh * 8;
        const _Float16* bp1 = latwT + (size_t)n1c * 400 + lh * 8;
        for (int ks = 0; ks < 25; ++ks) {
            half8 a  = *(const half8*)(ap  + ks * 16);
            acc0 = __builtin_amdgcn_mfma_f32_32x32x16_f16(a, *(const half8*)(bp0 + ks * 16), acc0, 0, 0, 0);
            acc1 = __builtin_amdgcn_mfma_f32_32x32x16_f16(a, *(const half8*)(bp1 + ks * 16), acc1, 0, 0, 0);
        }
    }
    __syncthreads();

    {
        float b0 = lat_b[n0c], b1v = lat_b[n1c];
        #pragma unroll
        for (int r = 0; r < 16; ++r) {
            int row = rm + (r & 3) + 8 * (r >> 2) + 4 * lh;
            int node = n0 + row;
            float v0 = acc0[r] + b0, v1 = acc1[r] + b1v;
            _Float16 h0 = (_Float16)v0, h1 = (_Float16)v1;
            if (node < N) {
                h[(size_t)node * HD + n0c] = v0;
                h[(size_t)node * HD + n1c] = v1;
                h16[(size_t)node * HD + n0c] = h0;
                h16[(size_t)node * HD + n1c] = h1;
            }
            xs[row * PST + n0c] = h0;
            xs[row * PST + n1c] = h1;
        }
    }
    __syncthreads();

    {
        const _Float16* BT  = (wv & 1) ? WbT : WaT;
        _Float16*       OUT = (wv & 1) ? Q16 : P16;
        floatx16 acc[4] = {};
        const _Float16* ap = xs + (size_t)(rm + l31) * PST + lh * 8;
        for (int ks = 0; ks < 8; ++ks) {
            half8 a = *(const half8*)(ap + ks * 16);
            #pragma unroll
            for (int i = 0; i < 4; ++i) {
                half8 b = *(const half8*)(BT + (size_t)(i * 32 + l31) * HD + ks * 16 + lh * 8);
                acc[i] = __builtin_amdgcn_mfma_f32_32x32x16_f16(a, b, acc[i], 0, 0, 0);
            }
        }
        #pragma unroll
        for (int r = 0; r < 16; ++r) {
            int row = rm + (r & 3) + 8 * (r >> 2) + 4 * lh;
            int node = n0 + row;
            if (node < N) {
                #pragma unroll
                for (int i = 0; i < 4; ++i)
                    OUT[(size_t)node * HD + i * 32 + l31] = (_Float16)acc[i][r];
            }
        }
    }
}

// ---- transposed edge kernel: weights = A operand, edges = B operand ----
// 64 edges/block, 4 waves. Wave (et = wv&1, M0 = (wv>>1)*64): 32 edges x 64 outcols.
// C-layout: col = edge (lane&31), rows = outcols -> b64 epilogues.
#define PUTF(kk, val) { const int _ks = (kk) >> 4, _j = (kk) & 15;                       \
    bfrag[_ks][_j & 7] = (lh == (_j >> 3)) ? (_Float16)(val) : bfrag[_ks][_j & 7]; }

template <bool LAST>
__global__ __launch_bounds__(256) void k_edge(
    const int* __restrict__ eaS, const int* __restrict__ ebS,
    const int* __restrict__ egS, const float* __restrict__ fdS,
    const _Float16* __restrict__ P16, const _Float16* __restrict__ Q16,
    const _Float16* __restrict__ R16, const _Float16* __restrict__ WdT,
    const _Float16* __restrict__ W2T, const float* __restrict__ b2,
    const _Float16* __restrict__ cw1T, const float* __restrict__ cb1,
    const float* __restrict__ cw2,
    float* __restrict__ aggsum, float* __restrict__ outsum, int E)
{
    __shared__ __align__(16) _Float16 xt[64 * PST];   // 17.4 KB: PQR -> x1 -> ef
    __shared__ int   eaL[64], ebL[64], egL[64];
    __shared__ float fdlL[64][3];
    __shared__ float gateL[64];

    int tid  = threadIdx.x;
    int lane = tid & 63, wv = tid >> 6;
    int l31  = lane & 31, lh = lane >> 5;
    int et   = wv & 1;              // edge tile (32 edges)
    int M0   = (wv >> 1) * 64;      // this wave's 2 col-tiles: M0..M0+63
    int e0   = et * 32;             // block-local edge base
    int s0   = blockIdx.x * 64;

    if (LAST && tid < 64) gateL[tid] = 0.f;

    // meta: lanes 0..31 of each wave load their et's rows (duplicate writes benign)
    if (lane < 32) {
        int row = e0 + l31;
        int s = s0 + row;
        if (s < E) {
            eaL[row] = eaS[s]; ebL[row] = ebS[s]; egL[row] = egS[s];
            fdlL[row][0] = fdS[s * 3];
            fdlL[row][1] = fdS[s * 3 + 1];
            fdlL[row][2] = fdS[s * 3 + 2];
        } else {
            eaL[row] = 0; ebL[row] = -1; egL[row] = 0;
            fdlL[row][0] = fdlL[row][1] = fdlL[row][2] = 0.f;
        }
    }

    // stage PQR for own region: 32 edges x 64 cols (M0..M0+63): 256 half8 / 64 lanes
    for (int i = lane; i < 32 * 8; i += 64) {
        int row = e0 + (i >> 3);
        int col = M0 + (i & 7) * 8;
        int b = ebL[row] < 0 ? 0 : ebL[row];
        half8 pv = *(const half8*)(P16 + (size_t)eaL[row] * HD + col);
        half8 qv = *(const half8*)(Q16 + (size_t)b * HD + col);
        half8 rv = *(const half8*)(R16 + (size_t)egL[row] * HD + col);
        *(half8*)(xt + row * PST + col) = pv + qv + rv;
    }

    int erow = e0 + l31;            // this lane's edge row

    // Chebyshev dis B-fragment (B[k][n=edge]: k = 16ks + 8lh + j)
    half8 bfrag[4];
    #pragma unroll
    for (int i = 0; i < 4; ++i)
        #pragma unroll
        for (int j = 0; j < 8; ++j) bfrag[i][j] = (_Float16)0.f;
    {
        float fdv[3] = {fdlL[erow][0], fdlL[erow][1], fdlL[erow][2]};
        #pragma unroll
        for (int d = 0; d < 3; ++d) {
            float ang = 6.283185307179586f * fdv[d];
            float s1 = __sinf(ang), c1 = __cosf(ang);
            float two_c1 = 2.f * c1;
            PUTF(30 + 10 * d + 0, 1.0f);      // cos w=0
            PUTF(10 * d + 1, s1);
            PUTF(30 + 10 * d + 1, c1);
            float sm2 = 0.f, sm1 = s1, cm2 = 1.f, cm1 = c1;
            #pragma unroll
            for (int wq = 2; wq < 10; ++wq) {
                float sn = two_c1 * sm1 - sm2;
                float cn = two_c1 * cm1 - cm2;
                PUTF(10 * d + wq, sn);
                PUTF(30 + 10 * d + wq, cn);
                sm2 = sm1; sm1 = sn; cm2 = cm1; cm1 = cn;
            }
        }
    }

    // ---- GEMM1 (transposed): Y' = Wd_A . dis_B, K=64, 2 M-tiles ----
    floatx16 acc[2] = {};
    #pragma unroll
    for (int ks = 0; ks < 4; ++ks) {
        #pragma unroll
        for (int c = 0; c < 2; ++c) {
            half8 a = *(const half8*)(WdT + (size_t)(M0 + c * 32 + l31) * 64 + ks * 16 + lh * 8);
            acc[c] = __builtin_amdgcn_mfma_f32_32x32x16_f16(a, bfrag[ks], acc[c], 0, 0, 0);
        }
    }

    // epilogue1: x1 = silu(Y' + PQR), in place, b64 accesses (own region only)
    #pragma unroll
    for (int c = 0; c < 2; ++c) {
        #pragma unroll
        for (int g = 0; g < 4; ++g) {
            int m = M0 + c * 32 + 4 * lh + 8 * g;
            half4v pq = *(const half4v*)(xt + erow * PST + m);
            half4v o;
            #pragma unroll
            for (int j = 0; j < 4; ++j)
                o[j] = (_Float16)silu_f(acc[c][g * 4 + j] + (float)pq[j]);
            *(half4v*)(xt + erow * PST + m) = o;
        }
    }
    __syncthreads();   // (1) x1 complete across waves

    // ---- GEMM2 (transposed): ef' = W2_A . x1_B, K=128 ----
    floatx16 acc2[2] = {};
    {
        const _Float16* bp = xt + (size_t)erow * PST + lh * 8;
        for (int ks = 0; ks < 8; ++ks) {
            half8 b = *(const half8*)(bp + ks * 16);
            #pragma unroll
            for (int c = 0; c < 2; ++c) {
                half8 a = *(const half8*)(W2T + (size_t)(M0 + c * 32 + l31) * HD + ks * 16 + lh * 8);
                acc2[c] = __builtin_amdgcn_mfma_f32_32x32x16_f16(a, b, acc2[c], 0, 0, 0);
            }
        }
    }
    // bias as float4 loads
    float4 b2f[2][4];
    #pragma unroll
    for (int c = 0; c < 2; ++c)
        #pragma unroll
        for (int g = 0; g < 4; ++g)
            b2f[c][g] = *(const float4*)(b2 + M0 + c * 32 + 4 * lh + 8 * g);
    __syncthreads();   // (2) x1 reads complete

    // ef -> xt in place
    #pragma unroll
    for (int c = 0; c < 2; ++c) {
        #pragma unroll
        for (int g = 0; g < 4; ++g) {
            int m = M0 + c * 32 + 4 * lh + 8 * g;
            const float* bb = (const float*)&b2f[c][g];
            half4v o;
            #pragma unroll
            for (int j = 0; j < 4; ++j)
                o[j] = (_Float16)silu_f(acc2[c][g * 4 + j] + bb[j]);
            *(half4v*)(xt + erow * PST + m) = o;
        }
    }
    __syncthreads();   // (3) ef complete

    if (!LAST) {
        // run-reduced scatter (edges sorted by dest): thread = 16 rows x 2 cols
        int c2 = (tid & 63) * 2;
        int r0s = (tid >> 6) * 16;
        float sx = 0.f, sy = 0.f;
        int cur = -1;
        for (int r = r0s; r < r0s + 16; ++r) {
            int d = ebL[r];
            half2v v = *(const half2v*)(xt + r * PST + c2);
            float vx = (float)v[0], vy = (float)v[1];
            if (d != cur) {
                if (cur >= 0) {
                    atomicAdd(&aggsum[(size_t)cur * HD + c2],     sx);
                    atomicAdd(&aggsum[(size_t)cur * HD + c2 + 1], sy);
                }
                cur = d; sx = vx; sy = vy;
            } else { sx += vx; sy += vy; }
        }
        if (cur >= 0) {
            atomicAdd(&aggsum[(size_t)cur * HD + c2],     sx);
            atomicAdd(&aggsum[(size_t)cur * HD + c2 + 1], sy);
        }
    } else {
        // GEMM3 (transposed): g1' = cw1_A . ef_B; gate[e] = sum_m silu(g1'+cb1)[m]*cw2[m]
        floatx16 acc3[2] = {};
        {
            const _Float16* bp = xt + (size_t)erow * PST + lh * 8;
            for (int ks = 0; ks < 8; ++ks) {
                half8 b = *(const half8*)(bp + ks * 16);
                #pragma unroll
                for (int c = 0; c < 2; ++c) {
                    half8 a = *(const half8*)(cw1T + (size_t)(M0 + c * 32 + l31) * HD + ks * 16 + lh * 8);
                    acc3[c] = __builtin_amdgcn_mfma_f32_32x32x16_f16(a, b, acc3[c], 0, 0, 0);
                }
            }
        }
        float p = 0.f;
        #pragma unroll
        for (int c = 0; c < 2; ++c) {
            #pragma unroll
            for (int g = 0; g < 4; ++g) {
                int m = M0 + c * 32 + 4 * lh + 8 * g;
                float4 cbf = *(const float4*)(cb1 + m);
                float4 cwf = *(const float4*)(cw2 + m);
                const float* cbp = (const float*)&cbf;
                const float* cwp = (const float*)&cwf;
                #pragma unroll
                for (int j = 0; j < 4; ++j)
                    p += silu_f(acc3[c][g * 4 + j] + cbp[j]) * cwp[j];
            }
        }
        p += __shfl_xor(p, 32);            // combine lane halves (disjoint m-sets)
        if (lh == 0) atomicAdd(&gateL[erow], p);   // 2 waves per et combine
        __syncthreads();   // (4) gate complete
        if (tid < 64) {
            int r = tid, d = ebL[r];
            if (d >= 0 && (r == 0 || ebL[r - 1] != d)) {
                float sx = 0.f, sy = 0.f, sz = 0.f;
                for (int q = r; q < 64 && ebL[q] == d; ++q) {
                    float g = gateL[q];
                    sx += fdlL[q][0] * g; sy += fdlL[q][1] * g; sz += fdlL[q][2] * g;
                }
                atomicAdd(&outsum[d * 3 + 0], sx);
                atomicAdd(&outsum[d * 3 + 1], sy);
                atomicAdd(&outsum[d * 3 + 2], sz);
            }
        }
    }
}

// ---- fused node update + next-layer P/Q (unchanged from R4) ----
__global__ __launch_bounds__(256) void k_node_pq(
    float* __restrict__ h, _Float16* __restrict__ h16,
    float* __restrict__ aggsum, const float* __restrict__ deginv,
    const _Float16* __restrict__ W1T, const float* __restrict__ b1,
    const _Float16* __restrict__ W2T, const float* __restrict__ b2,
    const _Float16* __restrict__ WaT, const _Float16* __restrict__ WbT,
    _Float16* __restrict__ P16, _Float16* __restrict__ Q16, int N)
{
    __shared__ __align__(16) _Float16 xs[64 * NST];   // 33.8 KB
    _Float16* x1s = xs;

    int tid = threadIdx.x;
    int n0  = blockIdx.x * 64;

    for (int c = tid; c < 64 * 16; c += 256) {
        int row = c >> 4, p = c & 15;
        int node = n0 + row;
        uint4 v = {0, 0, 0, 0};
        if (node < N) v = *(const uint4*)(h16 + (size_t)node * HD + p * 8);
        *(uint4*)(xs + row * NST + p * 8) = v;
    }
    for (int c = tid; c < 64 * HD; c += 256) {
        int row = c >> 7, cc = c & 127;
        int node = n0 + row;
        float v = 0.f;
        if (node < N) {
            size_t gi = (size_t)node * HD + cc;
            v = aggsum[gi] * deginv[node];
            aggsum[gi] = 0.f;
        }
        xs[row * NST + HD + cc] = (_Float16)v;
    }
    __syncthreads();

    int lane = tid & 63, wv = tid >> 6;
    int l31 = lane & 31, lh = lane >> 5;
    int rm = (wv >> 1) * 32, cbase = (wv & 1) * 64;
    int n0c = cbase + l31, n1c = cbase + 32 + l31;

    floatx16 acc0 = {}, acc1 = {};
    {
        const _Float16* ap  = xs  + (size_t)(rm + l31) * NST + lh * 8;
        const _Float16* bp0 = W1T + (size_t)n0c * 256 + lh * 8;
        const _Float16* bp1 = W1T + (size_t)n1c * 256 + lh * 8;
        for (int ks = 0; ks < 16; ++ks) {
            half8 a  = *(const half8*)(ap  + ks * 16);
            acc0 = __builtin_amdgcn_mfma_f32_32x32x16_f16(a, *(const half8*)(bp0 + ks * 16), acc0, 0, 0, 0);
            acc1 = __builtin_amdgcn_mfma_f32_32x32x16_f16(a, *(const half8*)(bp1 + ks * 16), acc1, 0, 0, 0);
        }
    }
    __syncthreads();
    {
        float b10 = b1[n0c], b11 = b1[n1c];
        #pragma unroll
        for (int r = 0; r < 16; ++r) {
            int row = rm + (r & 3) + 8 * (r >> 2) + 4 * lh;
            x1s[row * XST + n0c] = (_Float16)silu_f(acc0[r] + b10);
            x1s[row * XST + n1c] = (_Float16)silu_f(acc1[r] + b11);
        }
    }
    __syncthreads();

    acc0 = {}; acc1 = {};
    {
        const _Float16* ap  = x1s + (size_t)(rm + l31) * XST + lh * 8;
        const _Float16* bp0 = W2T + (size_t)n0c * HD + lh * 8;
        const _Float16* bp1 = W2T + (size_t)n1c * HD + lh * 8;
        for (int ks = 0; ks < 8; ++ks) {
            half8 a  = *(const half8*)(ap  + ks * 16);
            acc0 = __builtin_amdgcn_mfma_f32_32x32x16_f16(a, *(const half8*)(bp0 + ks * 16), acc0, 0, 0, 0);
            acc1 = __builtin_amdgcn_mfma_f32_32x32x16_f16(a, *(const half8*)(bp1 + ks * 16), acc1, 0, 0, 0);
        }
    }
    __syncthreads();

    {
        float b20 = b2[n0c], b21 = b2[n1c];
        #pragma unroll
        for (int r = 0; r < 16; ++r) {
            int row = rm + (r & 3) + 8 * (r >> 2) + 4 * lh;
            int node = n0 + row;
            float v0 = silu_f(acc0[r] + b20);
            float v1 = silu_f(acc1[r] + b21);
            _Float16 h0 = (_Float16)0.f, h1 = (_Float16)0.f;
            if (node < N) {
                size_t g0 = (size_t)node * HD + n0c;
                size_t g1 = (size_t)node * HD + n1c;
                v0 += h[g0]; v1 += h[g1];
                h[g0] = v0; h[g1] = v1;
                h0 = (_Float16)v0; h1 = (_Float16)v1;
                h16[g0] = h0; h16[g1] = h1;
            }
            xs[row * PST + n0c] = h0;
            xs[row * PST + n1c] = h1;
        }
    }
    __syncthreads();

    {
        const _Float16* BT  = (wv & 1) ? WbT : WaT;
        _Float16*       OUT = (wv & 1) ? Q16 : P16;
        floatx16 acc[4] = {};
        const _Float16* ap = xs + (size_t)(rm + l31) * PST + lh * 8;
        for (int ks = 0; ks < 8; ++ks) {
            half8 a = *(const half8*)(ap + ks * 16);
            #pragma unroll
            for (int i = 0; i < 4; ++i) {
                half8 b = *(const half8*)(BT + (size_t)(i * 32 + l31) * HD + ks * 16 + lh * 8);
                acc[i] = __builtin_amdgcn_mfma_f32_32x32x16_f16(a, b, acc[i], 0, 0, 0);
            }
        }
        #pragma unroll
        for (int r = 0; r < 16; ++r) {
            int row = rm + (r & 3) + 8 * (r >> 2) + 4 * lh;
            int node = n0 + row;
            if (node < N) {
                #pragma unroll
                for (int i = 0; i < 4; ++i)
                    OUT[(size_t)node * HD + i * 32 + l31] = (_Float16)acc[i][r];
            }
        }
    }
}

// ---------------- launcher ----------------
extern "C" void kernel_launch(void* const* d_in, const int* in_sizes, int n_in,
                              void* d_out, int out_size, void* d_ws, size_t ws_size,
                              hipStream_t stream)
{
    const int*   at    = (const int*)  d_in[0];
    const float* t     = (const float*)d_in[1];
    const float* fc    = (const float*)d_in[2];
    const int*   ei    = (const int*)  d_in[3];
    const float* lat   = (const float*)d_in[4];
    const int*   n2g   = (const int*)  d_in[5];
    const float* embed = (const float*)d_in[6];
    const float* lat_w = (const float*)d_in[7];
    const float* lat_b = (const float*)d_in[8];
    const float* ew1   = (const float*)d_in[9];
    const float* eb1   = (const float*)d_in[10];
    const float* ew2   = (const float*)d_in[11];
    const float* eb2   = (const float*)d_in[12];
    const float* nw1   = (const float*)d_in[13];
    const float* nb1   = (const float*)d_in[14];
    const float* nw2   = (const float*)d_in[15];
    const float* nb2   = (const float*)d_in[16];
    const float* cw1   = (const float*)d_in[17];
    const float* cb1   = (const float*)d_in[18];
    const float* cw2   = (const float*)d_in[19];

    int N = in_sizes[0];
    int E = in_sizes[3] / 2;
    int G = in_sizes[4] / 9;

    // ---- workspace carve ----
    char* p = (char*)d_ws;
    float* h      = (float*)p;  p += (size_t)N * HD * 4;
    float* aggsum = (float*)p;  p += (size_t)N * HD * 4;   // zeroed below
    float* outsum = (float*)p;  p += (size_t)N * 3 * 4;    // zeroed below
    int*   cnt    = (int*)p;    p += (size_t)N * 4;        // zeroed below
    int*   head   = (int*)p;    p += (size_t)N * 4;
    float* deginv = (float*)p;  p += (size_t)N * 4;
    float* latip  = (float*)p;  p += (size_t)G * 9 * 4;
    int*   perm   = (int*)p;    p += (size_t)E * 4;
    int*   eaS    = (int*)p;    p += (size_t)E * 4;
    int*   ebS    = (int*)p;    p += (size_t)E * 4;
    int*   egS    = (int*)p;    p += (size_t)E * 4;
    float* fdS    = (float*)p;  p += (size_t)E * 3 * 4;
    _Float16* h16   = (_Float16*)p; p += (size_t)N * HD * 2;
    _Float16* P16   = (_Float16*)p; p += (size_t)N * HD * 2;
    _Float16* Q16   = (_Float16*)p; p += (size_t)N * HD * 2;
    _Float16* w1aT  = (_Float16*)p; p += (size_t)4 * HD * HD * 2;
    _Float16* w1bT  = (_Float16*)p; p += (size_t)4 * HD * HD * 2;
    _Float16* wdT   = (_Float16*)p; p += (size_t)4 * HD * 64 * 2;
    _Float16* w2T   = (_Float16*)p; p += (size_t)4 * HD * HD * 2;
    _Float16* nw1T  = (_Float16*)p; p += (size_t)3 * HD * 256 * 2;
    _Float16* nw2T  = (_Float16*)p; p += (size_t)3 * HD * HD * 2;
    _Float16* cw1T  = (_Float16*)p; p += (size_t)HD * HD * 2;
    _Float16* latwT = (_Float16*)p; p += (size_t)HD * 400 * 2;
    _Float16* R16   = (_Float16*)p; p += (size_t)4 * G * HD * 2;

    // zero aggsum|outsum|cnt (contiguous)
    hipMemsetAsync(aggsum, 0, ((size_t)N * HD + (size_t)N * 3 + N) * 4, stream);

    // weight prep (fp16, transposed, K-padded)
    {
        int tot;
        tot = 4 * HD * HD;  k_wprep<<<(tot+255)/256, 256, 0, stream>>>(ew1, w1aT, EIN, 0,   128, HD, HD, 4);
        tot = 4 * HD * HD;  k_wprep<<<(tot+255)/256, 256, 0, stream>>>(ew1, w1bT, EIN, 128, 128, HD, HD, 4);
        tot = 4 * HD * 64;  k_wprep<<<(tot+255)/256, 256, 0, stream>>>(ew1, wdT,  EIN, 265, 60,  HD, 64, 4);
        tot = 4 * HD * HD;  k_wprep<<<(tot+255)/256, 256, 0, stream>>>(ew2, w2T,  HD,  0,  128, HD, HD, 4);
        tot = 3 * HD * 256; k_wprep<<<(tot+255)/256, 256, 0, stream>>>(nw1, nw1T, 256, 0,  256, HD, 256, 3);
        tot = 3 * HD * HD;  k_wprep<<<(tot+255)/256, 256, 0, stream>>>(nw2, nw2T, HD,  0,  128, HD, HD, 3);
        tot = 1 * HD * HD;  k_wprep<<<(tot+255)/256, 256, 0, stream>>>(cw1, cw1T, HD,  0,  128, HD, HD, 1);
        tot = HD * 400;     k_wprep<<<(tot+255)/256, 256, 0, stream>>>(lat_w, latwT, 384, 0, 384, HD, 400, 1);
    }

    k_latip  <<<(G * 9 + 255) / 256, 256, 0, stream>>>(lat, latip, G);
    k_hist   <<<(E + 255) / 256,     256, 0, stream>>>(ei + E, cnt, E);
    k_scan   <<<1, 1024, 0, stream>>>(cnt, head, N);
    k_deginv <<<(N + 255) / 256,     256, 0, stream>>>(cnt, deginv, N);
    k_scatter<<<(E + 255) / 256,     256, 0, stream>>>(ei + E, head, perm, E);
    k_esort  <<<(E + 255) / 256,     256, 0, stream>>>(ei, n2g, fc, perm, eaS, ebS, egS, fdS, E);
    k_rlat   <<<(4 * G * HD + 255) / 256, 256, 0, stream>>>(latip, ew1, eb1, R16, G);
    k_init_pq<<<(N + 63) / 64, 256, 0, stream>>>(at, t, embed, latwT, lat_b, h, h16,
                                                 w1aT, w1bT, P16, Q16, N);

    int eblocks = (E + 63) / 64;
    int nblocks = (N + 63) / 64;
    for (int l = 0; l < 3; ++l) {
        k_edge<false><<<eblocks, 256, 0, stream>>>(eaS, ebS, egS, fdS, P16, Q16,
            R16 + (size_t)l * G * HD, wdT + (size_t)l * HD * 64,
            w2T + (size_t)l * HD * HD, eb2 + l * HD,
            cw1T, cb1, cw2, aggsum, outsum, E);
        k_node_pq<<<nblocks, 256, 0, stream>>>(h, h16, aggsum, deginv,
            nw1T + (size_t)l * HD * 256, nb1 + l * HD,
            nw2T + (size_t)l * HD * HD,  nb2 + l * HD,
            w1aT + (size_t)(l + 1) * HD * HD, w1bT + (size_t)(l + 1) * HD * HD,
            P16, Q16, N);
    }
    k_edge<true><<<eblocks, 256, 0, stream>>>(eaS, ebS, egS, fdS, P16, Q16,
        R16 + (size_t)3 * G * HD, wdT + (size_t)3 * HD * 64,
        w2T + (size_t)3 * HD * HD, eb2 + 3 * HD,
        cw1T, cb1, cw2, aggsum, outsum, E);

    k_fin<<<(N * 3 + 255) / 256, 256, 0, stream>>>(outsum, deginv, (float*)d_out, N);
}